// Round 17
// baseline (375.523 us; speedup 1.0000x reference)
//
#include <hip/hip_runtime.h>
#include <math.h>

#define B_   32
#define M_   1024
#define H_   8
#define DH_  128
#define D_   1024

typedef __attribute__((ext_vector_type(8))) short short8v;     // 8 bf16 = 4 VGPR (MFMA frag)
typedef __attribute__((ext_vector_type(4))) float f32x4;
typedef __attribute__((ext_vector_type(8))) unsigned short ushort8v;
typedef __attribute__((ext_vector_type(4))) unsigned short ushort4v;

__device__ __forceinline__ float bf2f(unsigned short h) {
    return __uint_as_float(((unsigned)h) << 16);
}
__device__ __forceinline__ unsigned short f2bf(float f) {
    unsigned u = __float_as_uint(f);
    u += 0x7fffu + ((u >> 16) & 1u);              // RNE
    return (unsigned short)(u >> 16);
}

// ---------------------------------------------------------------------------
// key fp32 -> bf16, ZERO LDS (full occupancy; memory-bound, needs TLP).
// ---------------------------------------------------------------------------
__global__ __launch_bounds__(256)
void f32_to_bf16_vec(const float* __restrict__ in, unsigned short* __restrict__ out)
{
    const size_t i = ((size_t)blockIdx.x * 256 + threadIdx.x) * 8;
    const float4 a = *reinterpret_cast<const float4*>(in + i);
    const float4 b = *reinterpret_cast<const float4*>(in + i + 4);
    ushort8v o;
    o[0]=f2bf(a.x); o[1]=f2bf(a.y); o[2]=f2bf(a.z); o[3]=f2bf(a.w);
    o[4]=f2bf(b.x); o[5]=f2bf(b.y); o[6]=f2bf(b.z); o[7]=f2bf(b.w);
    *reinterpret_cast<ushort8v*>(out + i) = o;
}

// ---------------------------------------------------------------------------
// prep_wq: weight transposes + q path in one launch (288 blocks).
// ---------------------------------------------------------------------------
__global__ __launch_bounds__(256)
void prep_wq(const float* __restrict__ Wk,   unsigned short* __restrict__ WkT,
             const float* __restrict__ Wb1,  unsigned short* __restrict__ Wb1T,
             const float* __restrict__ Wa,   unsigned short* __restrict__ WaT,
             const float* __restrict__ query, const float* __restrict__ Wq,
             const float* __restrict__ bq,   const float* __restrict__ gqw,
             const float* __restrict__ gqb,  float* __restrict__ qbuf)
{
    __shared__ __align__(16) char pmem[59392];
    const int bid = blockIdx.x;
    const int tid = threadIdx.x;

    if (bid < 280) {
        float (*t)[65] = reinterpret_cast<float(*)[65]>(pmem);
        if (bid < 256) {
            const int k0 = (bid & 15) * 64;
            const int n0 = (bid >> 4) * 64;
            for (int i = tid; i < 4096; i += 256) {
                const int kk = i >> 6, nn = i & 63;
                t[kk][nn] = Wk[(size_t)(k0 + kk) * D_ + n0 + nn];
            }
            __syncthreads();
            for (int i = tid; i < 4096; i += 256) {
                const int nn = i >> 6, kk = i & 63;
                WkT[(size_t)(n0 + nn) * D_ + k0 + kk] = f2bf(t[kk][nn]);
            }
        } else if (bid < 264) {
            const int id2 = bid - 256;
            const int k0 = (id2 & 1) * 64;
            const int n0 = ((id2 >> 1) & 3) * 64;
            for (int i = tid; i < 4096; i += 256) {
                const int kk = i >> 6, nn = i & 63;
                t[kk][nn] = Wb1[(size_t)(k0 + kk) * 256 + n0 + nn];
            }
            __syncthreads();
            for (int i = tid; i < 4096; i += 256) {
                const int nn = i >> 6, kk = i & 63;
                Wb1T[(size_t)(n0 + nn) * 128 + k0 + kk] = f2bf(t[kk][nn]);
            }
        } else {
            const int k0 = (bid - 264) * 64;
            for (int i = tid; i < 4096; i += 256) {
                const int kk = i >> 6, nn = i & 63;
                t[kk][nn] = Wa[(size_t)(k0 + kk) * 64 + nn];
            }
            __syncthreads();
            for (int i = tid; i < 4096; i += 256) {
                const int nn = i >> 6, kk = i & 63;
                WaT[(size_t)nn * 1024 + k0 + kk] = f2bf(t[kk][nn]);
            }
        }
        return;
    }

    // ---- q path: GN(celu(query @ Wq + bq)), 32 rows, col tile = 128 ----
    {
        float (*As)[65]  = reinterpret_cast<float(*)[65]>(pmem);
        float (*Bs)[132] = reinterpret_cast<float(*)[132]>(pmem + 8320);
        float (*Cs)[132] = reinterpret_cast<float(*)[132]>(pmem + 25216);

        const int col0 = (bid - 280) * 128;
        const int ty = tid >> 4;
        const int tx = tid & 15;

        float acc[4][8];
        #pragma unroll
        for (int i = 0; i < 4; ++i)
            #pragma unroll
            for (int j = 0; j < 8; ++j) acc[i][j] = 0.f;

        const int am = tid >> 2;
        const int ak = (tid & 3) * 8;
        const int bk_ = tid >> 3;
        const int bn_ = (tid & 7) * 16;

        for (int kt = 0; kt < D_; kt += 32) {
            {
                float4 v0 = make_float4(0.f,0.f,0.f,0.f), v1 = v0;
                if (am < B_) {
                    const float4* p = reinterpret_cast<const float4*>(&query[(size_t)am * D_ + kt + ak]);
                    v0 = p[0]; v1 = p[1];
                }
                As[ak + 0][am] = v0.x; As[ak + 1][am] = v0.y;
                As[ak + 2][am] = v0.z; As[ak + 3][am] = v0.w;
                As[ak + 4][am] = v1.x; As[ak + 5][am] = v1.y;
                As[ak + 6][am] = v1.z; As[ak + 7][am] = v1.w;
            }
            {
                const float4* p = reinterpret_cast<const float4*>(&Wq[(size_t)(kt + bk_) * D_ + col0 + bn_]);
                float4 w0 = p[0], w1 = p[1], w2 = p[2], w3 = p[3];
                *reinterpret_cast<float4*>(&Bs[bk_][bn_ + 0])  = w0;
                *reinterpret_cast<float4*>(&Bs[bk_][bn_ + 4])  = w1;
                *reinterpret_cast<float4*>(&Bs[bk_][bn_ + 8])  = w2;
                *reinterpret_cast<float4*>(&Bs[bk_][bn_ + 12]) = w3;
            }
            __syncthreads();
            #pragma unroll
            for (int k = 0; k < 32; ++k) {
                float aa[4];
                aa[0] = As[k][ty*4+0]; aa[1] = As[k][ty*4+1];
                aa[2] = As[k][ty*4+2]; aa[3] = As[k][ty*4+3];
                float4 b0 = *reinterpret_cast<const float4*>(&Bs[k][tx*8]);
                float4 b1 = *reinterpret_cast<const float4*>(&Bs[k][tx*8+4]);
                float bb[8] = {b0.x,b0.y,b0.z,b0.w,b1.x,b1.y,b1.z,b1.w};
                #pragma unroll
                for (int i = 0; i < 4; ++i)
                    #pragma unroll
                    for (int j = 0; j < 8; ++j)
                        acc[i][j] += aa[i] * bb[j];
            }
            __syncthreads();
        }

        #pragma unroll
        for (int i = 0; i < 4; ++i) {
            const int r = ty*4 + i;
            #pragma unroll
            for (int j = 0; j < 8; ++j) {
                const int c = tx*8 + j;
                float v = acc[i][j] + bq[col0 + c];
                v = v > 0.f ? v : expm1f(v);
                Cs[r][c] = v;
            }
        }
        __syncthreads();

        const int r   = tid >> 2;
        const int seg = (tid & 3) * 32;
        float s = 0.f, s2 = 0.f;
        #pragma unroll
        for (int e = 0; e < 32; e += 4) {
            float4 v = *reinterpret_cast<const float4*>(&Cs[r][seg + e]);
            s  += v.x + v.y + v.z + v.w;
            s2 += v.x*v.x + v.y*v.y + v.z*v.z + v.w*v.w;
        }
        s  += __shfl_xor(s, 1);  s2 += __shfl_xor(s2, 1);
        s  += __shfl_xor(s, 2);  s2 += __shfl_xor(s2, 2);
        const float mu   = s * (1.f/128.f);
        const float var  = s2 * (1.f/128.f) - mu*mu;
        const float rstd = rsqrtf(var + 1e-5f);
        if (r < B_) {
            #pragma unroll
            for (int e = 0; e < 32; e += 4) {
                const int c = seg + e;
                float4 v  = *reinterpret_cast<const float4*>(&Cs[r][c]);
                float4 gm = *reinterpret_cast<const float4*>(&gqw[col0 + c]);
                float4 be = *reinterpret_cast<const float4*>(&gqb[col0 + c]);
                float4 o;
                o.x = (v.x - mu)*rstd*gm.x + be.x;
                o.y = (v.y - mu)*rstd*gm.y + be.y;
                o.z = (v.z - mu)*rstd*gm.z + be.z;
                o.w = (v.w - mu)*rstd*gm.w + be.w;
                *reinterpret_cast<float4*>(&qbuf[(size_t)r * D_ + col0 + c]) = o;
            }
        }
    }
}

// ---------------------------------------------------------------------------
// K2 (FUSED): bf16 MFMA GEMM (128x128, BK=64) + celu + GN(128) + pool + gate.
// R17: B operand read DIRECTLY from global (L2-resident 256KB panel per
// col-tile with the same-XCD swizzle) — no B staging, no B ds_reads.
// LDS 64->38.5KB => 4 blocks/CU resident (was 2, LDS-capped): doubles the
// cross-block TLP that hides the per-K-step barrier drain (m114 mechanism).
// A path, arithmetic and output are bit-identical to R16.
// (R12 lesson: never hoist Wb1T frags across the barrier — 128-VGPR cliff.)
// ---------------------------------------------------------------------------
__global__ __launch_bounds__(256)
void gemm_fused(const unsigned short* __restrict__ Ab,
                const unsigned short* __restrict__ Bt,
                const float* __restrict__ bias, const float* __restrict__ gamma,
                const float* __restrict__ beta,
                const float* __restrict__ qbuf,
                const unsigned short* __restrict__ wb1t,
                const float* __restrict__ bb1,
                const float* __restrict__ mask,
                unsigned short* __restrict__ outb)
{
    __shared__ __align__(16) char smem[39424];
    unsigned short* AsP = (unsigned short*)smem;              // A staging [2][8192] elems (32KB)
    unsigned short* Asr = (unsigned short*)smem;              // reuse: A [128][136]
    float* sums_l = (float*)(smem + 34816);                   // [2][128]
    float* sqs_l  = (float*)(smem + 35840);                   // [2][128]
    float* redp   = (float*)(smem + 36864);                   // [4][128]
    float* alphap = (float*)(smem + 38912);                   // [128]

    const int tid = threadIdx.x;
    const int l   = tid & 63;
    const int wid = tid >> 6;
    const int wr  = wid >> 1;
    const int wc  = wid & 1;
    const int lr  = l & 15;
    const int kg  = l >> 4;

    // ---- same-XCD temporal swizzle (bijective over 2048) ----
    const int bid = blockIdx.x;
    const int xcd = bid & 7;
    const int w8  = bid >> 3;
    const int c   = w8 & 7;               // col tile 0..7
    const int rs  = (w8 >> 3) * 8 + xcd;  // row stripe 0..255
    const size_t row0 = (size_t)rs * 128;
    const int    col0 = c * 128;

    // ---- A staging addresses (pre-swizzled global source, linear LDS dest) ----
    const int sr0  = wid * 32 + (l >> 2);
    const int ksrc = (((l & 3) ^ ((sr0 >> 1) & 3)) << 3);
    const unsigned short* gA0 = Ab + (row0 + sr0) * D_ + ksrc;
    const unsigned short* gA1 = Ab + (row0 + sr0 + 16) * D_ + ksrc;
    const int ldsoA0 = wid * 1024;        // elems, within a 4096-elem half-panel

    // ---- B fragment base in GLOBAL (k-contiguous rows of WkT) ----
    // frag n (k-half h, K-step t): 8 bf16 at WkT[(col0 + wc*64 + n*16 + lr)][t*64 + h*32 + kg*8]
    const unsigned short* gBbase =
        Bt + (size_t)(col0 + wc * 64 + lr) * D_ + kg * 8;

    int aoff[4];                          // byte offsets within an 8192B half-panel
    #pragma unroll
    for (int m = 0; m < 4; ++m) {
        const int rowf = wr * 64 + m * 16 + lr;
        aoff[m] = rowf * 64 + ((kg ^ ((rowf >> 1) & 3)) << 4);
    }

    f32x4 acc[4][4];
    #pragma unroll
    for (int m = 0; m < 4; ++m)
        #pragma unroll
        for (int n = 0; n < 4; ++n) acc[m][n] = (f32x4)(0.f);

    // 4 issues/thread per K-step: A x {row, row+16} x {k-half 0, 1}
    #define GLD(src, dstoff)                                                            \
        __builtin_amdgcn_global_load_lds(                                               \
            (const __attribute__((address_space(1))) void*)(src),                       \
            (__attribute__((address_space(3))) void*)(dstoff), 16, 0, 0)
    #define STAGE(buf, kt)                                                              \
        do {                                                                            \
            GLD(gA0 + (kt),      &AsP[(buf)*8192 + ldsoA0]);                            \
            GLD(gA1 + (kt),      &AsP[(buf)*8192 + ldsoA0 + 512]);                      \
            GLD(gA0 + (kt) + 32, &AsP[(buf)*8192 + 4096 + ldsoA0]);                     \
            GLD(gA1 + (kt) + 32, &AsP[(buf)*8192 + 4096 + ldsoA0 + 512]);               \
        } while (0)

    STAGE(0, 0);
    __syncthreads();

    int cur = 0;
    for (int t = 0; t < 16; ++t) {
        if (t + 1 < 16) STAGE(cur ^ 1, (t + 1) * 64);   // prefetch next A K-step

        const char* baseA = (const char*)smem + cur * 16384;
        #pragma unroll
        for (int h = 0; h < 2; ++h) {                    // two 32-K half-phases
            short8v a[4], b[4];
            #pragma unroll
            for (int m = 0; m < 4; ++m)
                a[m] = *reinterpret_cast<const short8v*>(baseA + h * 8192 + aoff[m]);
            #pragma unroll
            for (int n = 0; n < 4; ++n)
                b[n] = *reinterpret_cast<const short8v*>(
                    gBbase + n * 16 * D_ + t * 64 + h * 32);
            #pragma unroll
            for (int m = 0; m < 4; ++m)
                #pragma unroll
                for (int n = 0; n < 4; ++n)
                    acc[m][n] = __builtin_amdgcn_mfma_f32_16x16x32_bf16(a[m], b[n], acc[m][n], 0, 0, 0);
        }

        __syncthreads();                   // drains A prefetch; next iter reads it
        cur ^= 1;
    }
    #undef STAGE
    #undef GLD

    // ---- bias + celu (fast exp; |err| ~1e-7 << tolerance) ----
    float bcol[4], gcol[4], btc[4];
    #pragma unroll
    for (int n = 0; n < 4; ++n) {
        const int cc = col0 + wc * 64 + n * 16 + lr;
        bcol[n] = bias[cc]; gcol[n] = gamma[cc]; btc[n] = beta[cc];
    }
    #pragma unroll
    for (int m = 0; m < 4; ++m)
        #pragma unroll
        for (int n = 0; n < 4; ++n) {
            f32x4 v = acc[m][n];
            #pragma unroll
            for (int r = 0; r < 4; ++r) {
                float x = v[r] + bcol[n];
                v[r] = x > 0.f ? x : __expf(x) - 1.f;
            }
            acc[m][n] = v;
        }

    // ---- GroupNorm stats ----
    float s[16], s2[16];
    #pragma unroll
    for (int m = 0; m < 4; ++m)
        #pragma unroll
        for (int r = 0; r < 4; ++r) {
            float t = 0.f, t2 = 0.f;
            #pragma unroll
            for (int n = 0; n < 4; ++n) {
                const float v = acc[m][n][r];
                t += v; t2 += v * v;
            }
            s[m * 4 + r] = t; s2[m * 4 + r] = t2;
        }
    #pragma unroll
    for (int i = 0; i < 16; ++i) {
        s[i]  += __shfl_xor(s[i], 1);  s2[i] += __shfl_xor(s2[i], 1);
        s[i]  += __shfl_xor(s[i], 2);  s2[i] += __shfl_xor(s2[i], 2);
        s[i]  += __shfl_xor(s[i], 4);  s2[i] += __shfl_xor(s2[i], 4);
        s[i]  += __shfl_xor(s[i], 8);  s2[i] += __shfl_xor(s2[i], 8);
    }
    if (lr == 0) {
        #pragma unroll
        for (int m = 0; m < 4; ++m)
            #pragma unroll
            for (int r = 0; r < 4; ++r) {
                const int rl = wr * 64 + m * 16 + kg * 4 + r;
                sums_l[wc * 128 + rl] = s[m * 4 + r];
                sqs_l[wc * 128 + rl]  = s2[m * 4 + r];
            }
    }
    __syncthreads();

    // ---- GN apply (knorm stays in acc) ----
    #pragma unroll
    for (int m = 0; m < 4; ++m)
        #pragma unroll
        for (int r = 0; r < 4; ++r) {
            const int rl = wr * 64 + m * 16 + kg * 4 + r;
            const float ts = sums_l[rl] + sums_l[128 + rl];
            const float tq = sqs_l[rl] + sqs_l[128 + rl];
            const float mu = ts * 0.0078125f;
            const float var = tq * 0.0078125f - mu * mu;
            const float rstd = rsqrtf(var + 1e-5f);
            #pragma unroll
            for (int n = 0; n < 4; ++n)
                acc[m][n][r] = (acc[m][n][r] - mu) * rstd * gcol[n] + btc[n];
        }

    // ---- pool phase: A = f2bf(knorm * q) -> LDS [128][136] ----
    const int b = (int)(row0 >> 10);
    float qcol[4];
    #pragma unroll
    for (int n = 0; n < 4; ++n)
        qcol[n] = qbuf[b * D_ + col0 + wc * 64 + n * 16 + lr];

    __syncthreads();   // staging region fully dead before Asr writes
    #pragma unroll
    for (int m = 0; m < 4; ++m)
        #pragma unroll
        for (int n = 0; n < 4; ++n) {
            const int cd = wc * 64 + n * 16 + lr;
            #pragma unroll
            for (int r = 0; r < 4; ++r) {
                const int rowl = wr * 64 + m * 16 + kg * 4 + r;
                Asr[rowl * 136 + cd] = f2bf(acc[m][n][r] * qcol[n]);
            }
        }
    __syncthreads();

    // ---- Wb1T frags for this wave's 64 cols (global, L2-hot) ----
    short8v bfr[4][4];
    float bb1c[4];
    #pragma unroll
    for (int ct = 0; ct < 4; ++ct) {
        const int colW = wid * 64 + ct * 16 + lr;
        bb1c[ct] = bb1[colW];
        #pragma unroll
        for (int ks = 0; ks < 4; ++ks)
            bfr[ct][ks] = *reinterpret_cast<const short8v*>(
                &wb1t[(size_t)colW * 128 + ks * 32 + kg * 8]);
    }

    // ---- pool MFMA per rowgroup + relu + rowsum ----
    #pragma unroll
    for (int rg = 0; rg < 8; ++rg) {
        short8v a2[4];
        #pragma unroll
        for (int ks = 0; ks < 4; ++ks)
            a2[ks] = *reinterpret_cast<const short8v*>(
                &Asr[(rg * 16 + lr) * 136 + ks * 32 + kg * 8]);
        f32x4 pacc[4];
        #pragma unroll
        for (int ct = 0; ct < 4; ++ct) pacc[ct] = (f32x4)(0.f);
        #pragma unroll
        for (int ks = 0; ks < 4; ++ks)
            #pragma unroll
            for (int ct = 0; ct < 4; ++ct)
                pacc[ct] = __builtin_amdgcn_mfma_f32_16x16x32_bf16(
                    a2[ks], bfr[ct][ks], pacc[ct], 0, 0, 0);
        #pragma unroll
        for (int r = 0; r < 4; ++r) {
            float t = 0.f;
            #pragma unroll
            for (int ct = 0; ct < 4; ++ct) {
                const float v = pacc[ct][r] + bb1c[ct];
                t += v > 0.f ? v : 0.f;
            }
            t += __shfl_xor(t, 1); t += __shfl_xor(t, 2);
            t += __shfl_xor(t, 4); t += __shfl_xor(t, 8);
            if (lr == 0) redp[wid * 128 + rg * 16 + kg * 4 + r] = t;
        }
    }
    __syncthreads();

    if (tid < 128) {
        float p = redp[tid] + redp[128 + tid] + redp[256 + tid] + redp[384 + tid];
        const float mk = mask[row0 + tid];
        p = p * mk / mk;                  // reference NaN semantics
        alphap[tid] = 1.f / (1.f + expf(-p));
    }
    __syncthreads();

    // ---- gated = acc*q*alpha, single-rounded store ----
    #pragma unroll
    for (int m = 0; m < 4; ++m)
        #pragma unroll
        for (int r = 0; r < 4; ++r) {
            const int rowl = wr * 64 + m * 16 + kg * 4 + r;
            const float al = alphap[rowl];
            #pragma unroll
            for (int n = 0; n < 4; ++n) {
                outb[(row0 + rowl) * D_ + col0 + wc * 64 + n * 16 + lr] =
                    f2bf(acc[m][n][r] * qcol[n] * al);
            }
        }
}

// ---------------------------------------------------------------------------
// K4 (MFMA): logits[row] = relu(gated[row,:] @ Wa + ba) @ Wl + bl.
// 128 rows/block (256 blocks), 2 row-halves per wave.
// ---------------------------------------------------------------------------
__global__ __launch_bounds__(256)
void attn_logits_mfma(const unsigned short* __restrict__ gated,
                      const unsigned short* __restrict__ wat,
                      const float* __restrict__ ba, const float* __restrict__ Wl,
                      const float* __restrict__ bl, float* __restrict__ logits)
{
    __shared__ __align__(16) unsigned short Bs[64 * 256];   // 32 KB

    const int tid = threadIdx.x;
    const int l   = tid & 63;
    const int w   = tid >> 6;
    const int lr  = l & 15;
    const int kg  = l >> 4;
    const size_t arow0 = (size_t)blockIdx.x * 128 + w * 16 + lr;       // half 0
    const size_t arow1 = arow0 + 64;                                    // half 1

    const int sc  = tid >> 2;          // staging col 0..63
    const int sg0 = (tid & 3) * 8;     // staging granule base

    f32x4 acc[2][4];
    #pragma unroll
    for (int hh = 0; hh < 2; ++hh)
        #pragma unroll
        for (int ct = 0; ct < 4; ++ct) acc[hh][ct] = (f32x4)(0.f);

    for (int chunk = 0; chunk < 4; ++chunk) {
        const int k0 = chunk * 256;
        __syncthreads();
        #pragma unroll
        for (int i = 0; i < 8; ++i) {
            const int gr = sg0 + i;
            const ushort8v v = *reinterpret_cast<const ushort8v*>(
                &wat[(size_t)sc * 1024 + k0 + gr * 8]);
            *reinterpret_cast<ushort8v*>(&Bs[sc * 256 + ((gr ^ (sc & 7)) << 3)]) = v;
        }
        __syncthreads();
        #pragma unroll
        for (int ks = 0; ks < 8; ++ks) {
            const short8v a0 = *reinterpret_cast<const short8v*>(
                &gated[arow0 * D_ + k0 + ks * 32 + kg * 8]);
            const short8v a1 = *reinterpret_cast<const short8v*>(
                &gated[arow1 * D_ + k0 + ks * 32 + kg * 8]);
            #pragma unroll
            for (int ct = 0; ct < 4; ++ct) {
                const int c  = ct * 16 + lr;
                const int gr = ks * 4 + kg;
                const short8v b = *reinterpret_cast<const short8v*>(
                    &Bs[c * 256 + ((gr ^ (c & 7)) << 3)]);
                acc[0][ct] = __builtin_amdgcn_mfma_f32_16x16x32_bf16(a0, b, acc[0][ct], 0, 0, 0);
                acc[1][ct] = __builtin_amdgcn_mfma_f32_16x16x32_bf16(a1, b, acc[1][ct], 0, 0, 0);
            }
        }
    }

    float bac[4], wlc[4];
    #pragma unroll
    for (int ct = 0; ct < 4; ++ct) {
        const int c = ct * 16 + lr;
        bac[ct] = ba[c]; wlc[ct] = Wl[c];
    }
    const float bl0 = bl[0];
    #pragma unroll
    for (int hh = 0; hh < 2; ++hh)
        #pragma unroll
        for (int r = 0; r < 4; ++r) {
            float t = 0.f;
            #pragma unroll
            for (int ct = 0; ct < 4; ++ct) {
                float v = acc[hh][ct][r] + bac[ct];
                v = v > 0.f ? v : 0.f;
                t += v * wlc[ct];
            }
            t += __shfl_xor(t, 1); t += __shfl_xor(t, 2);
            t += __shfl_xor(t, 4); t += __shfl_xor(t, 8);
            if (lr == 0)
                logits[blockIdx.x * 128 + hh * 64 + w * 16 + kg * 4 + r] = t + bl0;
        }
}

// ---------------------------------------------------------------------------
// K5b: fused softmax-stats + partial weighted sums.
// ---------------------------------------------------------------------------
__global__ __launch_bounds__(256)
void weighted_partial(const unsigned short* __restrict__ gated,
                      const float* __restrict__ logits,
                      float* __restrict__ part)
{
    __shared__ float red[256];
    __shared__ float w[32];
    const int b  = blockIdx.x >> 5;
    const int ch = blockIdx.x & 31;
    const int tid = threadIdx.x;

    // block-wide max over this batch's 1024 logits
    const float4 lg = *reinterpret_cast<const float4*>(&logits[b * M_ + tid * 4]);
    float mx = fmaxf(fmaxf(lg.x, lg.y), fmaxf(lg.z, lg.w));
    red[tid] = mx; __syncthreads();
    for (int s = 128; s > 0; s >>= 1) {
        if (tid < s) red[tid] = fmaxf(red[tid], red[tid + s]);
        __syncthreads();
    }
    mx = red[0]; __syncthreads();
    // block-wide denom
    float sm = expf(lg.x - mx) + expf(lg.y - mx) + expf(lg.z - mx) + expf(lg.w - mx);
    red[tid] = sm; __syncthreads();
    for (int s = 128; s > 0; s >>= 1) {
        if (tid < s) red[tid] += red[tid + s];
        __syncthreads();
    }
    const float dn = red[0];
    __syncthreads();

    if (tid < 32) {
        const int m = ch * 32 + tid;
        w[tid] = expf(logits[b * M_ + m] - mx) / dn;
    }
    __syncthreads();

    float acc[4] = {0.f, 0.f, 0.f, 0.f};
    const int d0 = tid * 4;
    for (int m = 0; m < 32; ++m) {
        const float wm = w[m];
        const ushort4v g4 = *reinterpret_cast<const ushort4v*>(
            &gated[(size_t)(b * M_ + ch * 32 + m) * D_ + d0]);
        acc[0] += wm * bf2f(g4[0]); acc[1] += wm * bf2f(g4[1]);
        acc[2] += wm * bf2f(g4[2]); acc[3] += wm * bf2f(g4[3]);
    }
    #pragma unroll
    for (int dd = 0; dd < 4; ++dd)
        part[(size_t)blockIdx.x * D_ + d0 + dd] = acc[dd];
}

// ---------------------------------------------------------------------------
// K5c: final reduce (32 partials per batch)
// ---------------------------------------------------------------------------
__global__ __launch_bounds__(256)
void final_reduce(const float* __restrict__ part, float* __restrict__ out)
{
    const int i = blockIdx.x * 256 + threadIdx.x;
    const int b = i >> 10, d = i & 1023;
    float s = 0.f;
    #pragma unroll
    for (int c = 0; c < 32; ++c) s += part[(size_t)(b*32 + c) * D_ + d];
    out[i] = s;
}

// ---------------------------------------------------------------------------
extern "C" void kernel_launch(void* const* d_in, const int* in_sizes, int n_in,
                              void* d_out, int out_size, void* d_ws, size_t ws_size,
                              hipStream_t stream)
{
    const float* query = (const float*)d_in[0];
    const float* key   = (const float*)d_in[1];
    const float* mask  = (const float*)d_in[2];
    const float* Wq  = (const float*)d_in[5];
    const float* bq  = (const float*)d_in[6];
    const float* gqw = (const float*)d_in[7];
    const float* gqb = (const float*)d_in[8];
    const float* Wk  = (const float*)d_in[9];
    const float* bk  = (const float*)d_in[10];
    const float* gkw = (const float*)d_in[11];
    const float* gkb = (const float*)d_in[12];
    const float* Wb1 = (const float*)d_in[21];
    const float* bb1 = (const float*)d_in[22];
    const float* Wa  = (const float*)d_in[23];
    const float* ba  = (const float*)d_in[24];
    const float* Wl  = (const float*)d_in[25];
    const float* bl  = (const float*)d_in[26];

    float* ws = (float*)d_ws;
    float* qbuf   = ws;                        //  32768 f
    float* logits = ws + 32768;                //  32768 f
    unsigned short* keyb = (unsigned short*)(ws + 327744);   // 33554432 bf16
    unsigned short* wtb  = keyb + 33554432;                  //  1048576 bf16
    unsigned short* kbuf = wtb + 1048576;                    // 33554432 bf16 (gated)
    unsigned short* wb1t = kbuf + 33554432;                  //    32768 bf16
    unsigned short* wat  = wb1t + 32768;                     //    65536 bf16
    float* part = (float*)keyb;   // keyb dead after gemm_fused; 4MB << 67MB

    // key convert: zero-LDS, full occupancy (memory-bound)
    f32_to_bf16_vec<<<16384, 256, 0, stream>>>(key, keyb);
    // weight transposes + q path in one small launch
    prep_wq<<<288, 256, 0, stream>>>(Wk, wtb, Wb1, wb1t, Wa, wat,
                                     query, Wq, bq, gqw, gqb, qbuf);

    // fused: k-proj + GN + pool + gate -> gated (kbuf); same-XCD swizzled grid
    gemm_fused<<<2048, 256, 0, stream>>>(keyb, wtb, bk, gkw, gkb,
                                         qbuf, wb1t, bb1, mask, kbuf);

    // logits (MFMA, 128 rows/block)
    attn_logits_mfma<<<256, 256, 0, stream>>>(kbuf, wat, ba, Wl, bl, logits);

    // fused softmax + weighted sum, then reduce
    weighted_partial<<<1024, 256, 0, stream>>>(kbuf, logits, part);
    final_reduce<<<128, 256, 0, stream>>>(part, (float*)d_out);
}

// Round 18
// 321.526 us; speedup vs baseline: 1.1679x; 1.1679x over previous
//
#include <hip/hip_runtime.h>
#include <math.h>

#define B_   32
#define M_   1024
#define H_   8
#define DH_  128
#define D_   1024

typedef __attribute__((ext_vector_type(8))) short short8v;     // 8 bf16 = 4 VGPR (MFMA frag)
typedef __attribute__((ext_vector_type(4))) float f32x4;
typedef __attribute__((ext_vector_type(8))) unsigned short ushort8v;
typedef __attribute__((ext_vector_type(4))) unsigned short ushort4v;

__device__ __forceinline__ float bf2f(unsigned short h) {
    return __uint_as_float(((unsigned)h) << 16);
}
__device__ __forceinline__ unsigned short f2bf(float f) {
    unsigned u = __float_as_uint(f);
    u += 0x7fffu + ((u >> 16) & 1u);              // RNE
    return (unsigned short)(u >> 16);
}

// ---------------------------------------------------------------------------
// key fp32 -> bf16, ZERO LDS (full occupancy; memory-bound, needs TLP).
// R15 lesson: merging this into a 59KB-LDS mega-kernel capped occupancy at
// 2 blocks/CU and ran at 742 GB/s instead of ~BW.
// ---------------------------------------------------------------------------
__global__ __launch_bounds__(256)
void f32_to_bf16_vec(const float* __restrict__ in, unsigned short* __restrict__ out)
{
    const size_t i = ((size_t)blockIdx.x * 256 + threadIdx.x) * 8;
    const float4 a = *reinterpret_cast<const float4*>(in + i);
    const float4 b = *reinterpret_cast<const float4*>(in + i + 4);
    ushort8v o;
    o[0]=f2bf(a.x); o[1]=f2bf(a.y); o[2]=f2bf(a.z); o[3]=f2bf(a.w);
    o[4]=f2bf(b.x); o[5]=f2bf(b.y); o[6]=f2bf(b.z); o[7]=f2bf(b.w);
    *reinterpret_cast<ushort8v*>(out + i) = o;
}

// ---------------------------------------------------------------------------
// prep_wq: weight transposes + q path in one launch (288 blocks).
//   blocks [0,256)  : Wk[1024][1024] -> WkT bf16
//   blocks [256,264): Wb1[128][256]  -> Wb1T bf16
//   blocks [264,280): Wa[1024][64]   -> WaT bf16
//   blocks [280,288): q = GN(celu(query @ Wq + bq))  (fp32, 8 col tiles)
// ---------------------------------------------------------------------------
__global__ __launch_bounds__(256)
void prep_wq(const float* __restrict__ Wk,   unsigned short* __restrict__ WkT,
             const float* __restrict__ Wb1,  unsigned short* __restrict__ Wb1T,
             const float* __restrict__ Wa,   unsigned short* __restrict__ WaT,
             const float* __restrict__ query, const float* __restrict__ Wq,
             const float* __restrict__ bq,   const float* __restrict__ gqw,
             const float* __restrict__ gqb,  float* __restrict__ qbuf)
{
    __shared__ __align__(16) char pmem[59392];
    const int bid = blockIdx.x;
    const int tid = threadIdx.x;

    if (bid < 280) {
        float (*t)[65] = reinterpret_cast<float(*)[65]>(pmem);
        if (bid < 256) {
            const int k0 = (bid & 15) * 64;
            const int n0 = (bid >> 4) * 64;
            for (int i = tid; i < 4096; i += 256) {
                const int kk = i >> 6, nn = i & 63;
                t[kk][nn] = Wk[(size_t)(k0 + kk) * D_ + n0 + nn];
            }
            __syncthreads();
            for (int i = tid; i < 4096; i += 256) {
                const int nn = i >> 6, kk = i & 63;
                WkT[(size_t)(n0 + nn) * D_ + k0 + kk] = f2bf(t[kk][nn]);
            }
        } else if (bid < 264) {
            const int id2 = bid - 256;
            const int k0 = (id2 & 1) * 64;
            const int n0 = ((id2 >> 1) & 3) * 64;
            for (int i = tid; i < 4096; i += 256) {
                const int kk = i >> 6, nn = i & 63;
                t[kk][nn] = Wb1[(size_t)(k0 + kk) * 256 + n0 + nn];
            }
            __syncthreads();
            for (int i = tid; i < 4096; i += 256) {
                const int nn = i >> 6, kk = i & 63;
                Wb1T[(size_t)(n0 + nn) * 128 + k0 + kk] = f2bf(t[kk][nn]);
            }
        } else {
            const int k0 = (bid - 264) * 64;
            for (int i = tid; i < 4096; i += 256) {
                const int kk = i >> 6, nn = i & 63;
                t[kk][nn] = Wa[(size_t)(k0 + kk) * 64 + nn];
            }
            __syncthreads();
            for (int i = tid; i < 4096; i += 256) {
                const int nn = i >> 6, kk = i & 63;
                WaT[(size_t)nn * 1024 + k0 + kk] = f2bf(t[kk][nn]);
            }
        }
        return;
    }

    // ---- q path: GN(celu(query @ Wq + bq)), 32 rows, col tile = 128 ----
    {
        float (*As)[65]  = reinterpret_cast<float(*)[65]>(pmem);
        float (*Bs)[132] = reinterpret_cast<float(*)[132]>(pmem + 8320);
        float (*Cs)[132] = reinterpret_cast<float(*)[132]>(pmem + 25216);

        const int col0 = (bid - 280) * 128;
        const int ty = tid >> 4;
        const int tx = tid & 15;

        float acc[4][8];
        #pragma unroll
        for (int i = 0; i < 4; ++i)
            #pragma unroll
            for (int j = 0; j < 8; ++j) acc[i][j] = 0.f;

        const int am = tid >> 2;
        const int ak = (tid & 3) * 8;
        const int bk_ = tid >> 3;
        const int bn_ = (tid & 7) * 16;

        for (int kt = 0; kt < D_; kt += 32) {
            {
                float4 v0 = make_float4(0.f,0.f,0.f,0.f), v1 = v0;
                if (am < B_) {
                    const float4* p = reinterpret_cast<const float4*>(&query[(size_t)am * D_ + kt + ak]);
                    v0 = p[0]; v1 = p[1];
                }
                As[ak + 0][am] = v0.x; As[ak + 1][am] = v0.y;
                As[ak + 2][am] = v0.z; As[ak + 3][am] = v0.w;
                As[ak + 4][am] = v1.x; As[ak + 5][am] = v1.y;
                As[ak + 6][am] = v1.z; As[ak + 7][am] = v1.w;
            }
            {
                const float4* p = reinterpret_cast<const float4*>(&Wq[(size_t)(kt + bk_) * D_ + col0 + bn_]);
                float4 w0 = p[0], w1 = p[1], w2 = p[2], w3 = p[3];
                *reinterpret_cast<float4*>(&Bs[bk_][bn_ + 0])  = w0;
                *reinterpret_cast<float4*>(&Bs[bk_][bn_ + 4])  = w1;
                *reinterpret_cast<float4*>(&Bs[bk_][bn_ + 8])  = w2;
                *reinterpret_cast<float4*>(&Bs[bk_][bn_ + 12]) = w3;
            }
            __syncthreads();
            #pragma unroll
            for (int k = 0; k < 32; ++k) {
                float aa[4];
                aa[0] = As[k][ty*4+0]; aa[1] = As[k][ty*4+1];
                aa[2] = As[k][ty*4+2]; aa[3] = As[k][ty*4+3];
                float4 b0 = *reinterpret_cast<const float4*>(&Bs[k][tx*8]);
                float4 b1 = *reinterpret_cast<const float4*>(&Bs[k][tx*8+4]);
                float bb[8] = {b0.x,b0.y,b0.z,b0.w,b1.x,b1.y,b1.z,b1.w};
                #pragma unroll
                for (int i = 0; i < 4; ++i)
                    #pragma unroll
                    for (int j = 0; j < 8; ++j)
                        acc[i][j] += aa[i] * bb[j];
            }
            __syncthreads();
        }

        #pragma unroll
        for (int i = 0; i < 4; ++i) {
            const int r = ty*4 + i;
            #pragma unroll
            for (int j = 0; j < 8; ++j) {
                const int c = tx*8 + j;
                float v = acc[i][j] + bq[col0 + c];
                v = v > 0.f ? v : expm1f(v);
                Cs[r][c] = v;
            }
        }
        __syncthreads();

        const int r   = tid >> 2;
        const int seg = (tid & 3) * 32;
        float s = 0.f, s2 = 0.f;
        #pragma unroll
        for (int e = 0; e < 32; e += 4) {
            float4 v = *reinterpret_cast<const float4*>(&Cs[r][seg + e]);
            s  += v.x + v.y + v.z + v.w;
            s2 += v.x*v.x + v.y*v.y + v.z*v.z + v.w*v.w;
        }
        s  += __shfl_xor(s, 1);  s2 += __shfl_xor(s2, 1);
        s  += __shfl_xor(s, 2);  s2 += __shfl_xor(s2, 2);
        const float mu   = s * (1.f/128.f);
        const float var  = s2 * (1.f/128.f) - mu*mu;
        const float rstd = rsqrtf(var + 1e-5f);
        if (r < B_) {
            #pragma unroll
            for (int e = 0; e < 32; e += 4) {
                const int c = seg + e;
                float4 v  = *reinterpret_cast<const float4*>(&Cs[r][c]);
                float4 gm = *reinterpret_cast<const float4*>(&gqw[col0 + c]);
                float4 be = *reinterpret_cast<const float4*>(&gqb[col0 + c]);
                float4 o;
                o.x = (v.x - mu)*rstd*gm.x + be.x;
                o.y = (v.y - mu)*rstd*gm.y + be.y;
                o.z = (v.z - mu)*rstd*gm.z + be.z;
                o.w = (v.w - mu)*rstd*gm.w + be.w;
                *reinterpret_cast<float4*>(&qbuf[(size_t)r * D_ + col0 + c]) = o;
            }
        }
    }
}

// ---------------------------------------------------------------------------
// K2 (FUSED): bf16 MFMA GEMM (128x128, BK=64) + celu + GN(128) + pool + gate.
// VERIFIED BEST (R16): VGPR 120, LDS 64KB, Occ 22%, 2 blocks/CU, 192us.
// Schedule-probe history (all on this kernel): R5 dbuf null, R6 counted-vmcnt
// null, R7 256-tile negative, R12 setprio+frag-hoist negative (VGPR cliff),
// R17 B-from-L2 negative (un-hidden L2 latency). Do not re-try these.
// ---------------------------------------------------------------------------
__global__ __launch_bounds__(256)
void gemm_fused(const unsigned short* __restrict__ Ab,
                const unsigned short* __restrict__ Bt,
                const float* __restrict__ bias, const float* __restrict__ gamma,
                const float* __restrict__ beta,
                const float* __restrict__ qbuf,
                const unsigned short* __restrict__ wb1t,
                const float* __restrict__ bb1,
                const float* __restrict__ mask,
                unsigned short* __restrict__ outb)
{
    __shared__ __align__(16) char smem[65536];
    unsigned short* AsP = (unsigned short*)smem;              // A staging [2][8192]
    unsigned short* BsP = (unsigned short*)(smem + 32768);    // B staging [2][8192]
    unsigned short* Asr = (unsigned short*)smem;              // reuse: A [128][136]
    float* sums_l = (float*)(smem + 34816);                   // [2][128]
    float* sqs_l  = (float*)(smem + 35840);                   // [2][128]
    float* redp   = (float*)(smem + 36864);                   // [4][128]
    float* alphap = (float*)(smem + 38912);                   // [128]

    const int tid = threadIdx.x;
    const int l   = tid & 63;
    const int wid = tid >> 6;
    const int wr  = wid >> 1;
    const int wc  = wid & 1;
    const int lr  = l & 15;
    const int kg  = l >> 4;

    // ---- same-XCD temporal swizzle (bijective over 2048) ----
    const int bid = blockIdx.x;
    const int xcd = bid & 7;
    const int w8  = bid >> 3;
    const int c   = w8 & 7;               // col tile 0..7
    const int rs  = (w8 >> 3) * 8 + xcd;  // row stripe 0..255
    const size_t row0 = (size_t)rs * 128;
    const int    col0 = c * 128;

    // ---- staging addresses (pre-swizzled global source, linear LDS dest) ----
    const int sr0  = wid * 32 + (l >> 2);
    const int ksrc = (((l & 3) ^ ((sr0 >> 1) & 3)) << 3);
    const unsigned short* gA0 = Ab + (row0 + sr0) * D_ + ksrc;
    const unsigned short* gA1 = Ab + (row0 + sr0 + 16) * D_ + ksrc;
    const unsigned short* gB0 = Bt + (size_t)(col0 + sr0) * D_ + ksrc;
    const unsigned short* gB1 = Bt + (size_t)(col0 + sr0 + 16) * D_ + ksrc;
    const int ldsoA0 = wid * 1024;        // elems, within a 4096-elem half-panel

    int aoff[4], boff[4];                 // byte offsets within an 8192B half-panel
    #pragma unroll
    for (int m = 0; m < 4; ++m) {
        const int rowf = wr * 64 + m * 16 + lr;
        aoff[m] = rowf * 64 + ((kg ^ ((rowf >> 1) & 3)) << 4);
        const int colf = wc * 64 + m * 16 + lr;
        boff[m] = colf * 64 + ((kg ^ ((colf >> 1) & 3)) << 4);
    }

    f32x4 acc[4][4];
    #pragma unroll
    for (int m = 0; m < 4; ++m)
        #pragma unroll
        for (int n = 0; n < 4; ++n) acc[m][n] = (f32x4)(0.f);

    // 8 issues/thread per K-step: A/B x {row, row+16} x {k-half 0, 1}
    #define GLD(src, dstoff)                                                            \
        __builtin_amdgcn_global_load_lds(                                               \
            (const __attribute__((address_space(1))) void*)(src),                       \
            (__attribute__((address_space(3))) void*)(dstoff), 16, 0, 0)
    #define STAGE(buf, kt)                                                              \
        do {                                                                            \
            GLD(gA0 + (kt),      &AsP[(buf)*8192 + ldsoA0]);                            \
            GLD(gA1 + (kt),      &AsP[(buf)*8192 + ldsoA0 + 512]);                      \
            GLD(gA0 + (kt) + 32, &AsP[(buf)*8192 + 4096 + ldsoA0]);                     \
            GLD(gA1 + (kt) + 32, &AsP[(buf)*8192 + 4096 + ldsoA0 + 512]);               \
            GLD(gB0 + (kt),      &BsP[(buf)*8192 + ldsoA0]);                            \
            GLD(gB1 + (kt),      &BsP[(buf)*8192 + ldsoA0 + 512]);                      \
            GLD(gB0 + (kt) + 32, &BsP[(buf)*8192 + 4096 + ldsoA0]);                     \
            GLD(gB1 + (kt) + 32, &BsP[(buf)*8192 + 4096 + ldsoA0 + 512]);               \
        } while (0)

    STAGE(0, 0);
    __syncthreads();

    int cur = 0;
    for (int t = 0; t < 16; ++t) {
        if (t + 1 < 16) STAGE(cur ^ 1, (t + 1) * 64);   // prefetch next K-step

        const char* baseA = (const char*)smem + cur * 16384;
        const char* baseB = (const char*)smem + 32768 + cur * 16384;
        #pragma unroll
        for (int h = 0; h < 2; ++h) {                    // two 32-K half-phases
            short8v a[4], b[4];
            #pragma unroll
            for (int m = 0; m < 4; ++m)
                a[m] = *reinterpret_cast<const short8v*>(baseA + h * 8192 + aoff[m]);
            #pragma unroll
            for (int n = 0; n < 4; ++n)
                b[n] = *reinterpret_cast<const short8v*>(baseB + h * 8192 + boff[n]);
            #pragma unroll
            for (int m = 0; m < 4; ++m)
                #pragma unroll
                for (int n = 0; n < 4; ++n)
                    acc[m][n] = __builtin_amdgcn_mfma_f32_16x16x32_bf16(a[m], b[n], acc[m][n], 0, 0, 0);
        }

        __syncthreads();                   // drains prefetch; next iter reads it
        cur ^= 1;
    }
    #undef STAGE
    #undef GLD

    // ---- bias + celu (fast exp; |err| ~1e-7 << tolerance) ----
    float bcol[4], gcol[4], btc[4];
    #pragma unroll
    for (int n = 0; n < 4; ++n) {
        const int cc = col0 + wc * 64 + n * 16 + lr;
        bcol[n] = bias[cc]; gcol[n] = gamma[cc]; btc[n] = beta[cc];
    }
    #pragma unroll
    for (int m = 0; m < 4; ++m)
        #pragma unroll
        for (int n = 0; n < 4; ++n) {
            f32x4 v = acc[m][n];
            #pragma unroll
            for (int r = 0; r < 4; ++r) {
                float x = v[r] + bcol[n];
                v[r] = x > 0.f ? x : __expf(x) - 1.f;
            }
            acc[m][n] = v;
        }

    // ---- GroupNorm stats ----
    float s[16], s2[16];
    #pragma unroll
    for (int m = 0; m < 4; ++m)
        #pragma unroll
        for (int r = 0; r < 4; ++r) {
            float t = 0.f, t2 = 0.f;
            #pragma unroll
            for (int n = 0; n < 4; ++n) {
                const float v = acc[m][n][r];
                t += v; t2 += v * v;
            }
            s[m * 4 + r] = t; s2[m * 4 + r] = t2;
        }
    #pragma unroll
    for (int i = 0; i < 16; ++i) {
        s[i]  += __shfl_xor(s[i], 1);  s2[i] += __shfl_xor(s2[i], 1);
        s[i]  += __shfl_xor(s[i], 2);  s2[i] += __shfl_xor(s2[i], 2);
        s[i]  += __shfl_xor(s[i], 4);  s2[i] += __shfl_xor(s2[i], 4);
        s[i]  += __shfl_xor(s[i], 8);  s2[i] += __shfl_xor(s2[i], 8);
    }
    if (lr == 0) {
        #pragma unroll
        for (int m = 0; m < 4; ++m)
            #pragma unroll
            for (int r = 0; r < 4; ++r) {
                const int rl = wr * 64 + m * 16 + kg * 4 + r;
                sums_l[wc * 128 + rl] = s[m * 4 + r];
                sqs_l[wc * 128 + rl]  = s2[m * 4 + r];
            }
    }
    __syncthreads();

    // ---- GN apply (knorm stays in acc) ----
    #pragma unroll
    for (int m = 0; m < 4; ++m)
        #pragma unroll
        for (int r = 0; r < 4; ++r) {
            const int rl = wr * 64 + m * 16 + kg * 4 + r;
            const float ts = sums_l[rl] + sums_l[128 + rl];
            const float tq = sqs_l[rl] + sqs_l[128 + rl];
            const float mu = ts * 0.0078125f;
            const float var = tq * 0.0078125f - mu * mu;
            const float rstd = rsqrtf(var + 1e-5f);
            #pragma unroll
            for (int n = 0; n < 4; ++n)
                acc[m][n][r] = (acc[m][n][r] - mu) * rstd * gcol[n] + btc[n];
        }

    // ---- pool phase: A = f2bf(knorm * q) -> LDS [128][136] ----
    const int b = (int)(row0 >> 10);
    float qcol[4];
    #pragma unroll
    for (int n = 0; n < 4; ++n)
        qcol[n] = qbuf[b * D_ + col0 + wc * 64 + n * 16 + lr];

    __syncthreads();   // staging region fully dead before Asr writes
    #pragma unroll
    for (int m = 0; m < 4; ++m)
        #pragma unroll
        for (int n = 0; n < 4; ++n) {
            const int cd = wc * 64 + n * 16 + lr;
            #pragma unroll
            for (int r = 0; r < 4; ++r) {
                const int rowl = wr * 64 + m * 16 + kg * 4 + r;
                Asr[rowl * 136 + cd] = f2bf(acc[m][n][r] * qcol[n]);
            }
        }
    __syncthreads();

    // ---- Wb1T frags for this wave's 64 cols (global, L2-hot) ----
    short8v bfr[4][4];
    float bb1c[4];
    #pragma unroll
    for (int ct = 0; ct < 4; ++ct) {
        const int colW = wid * 64 + ct * 16 + lr;
        bb1c[ct] = bb1[colW];
        #pragma unroll
        for (int ks = 0; ks < 4; ++ks)
            bfr[ct][ks] = *reinterpret_cast<const short8v*>(
                &wb1t[(size_t)colW * 128 + ks * 32 + kg * 8]);
    }

    // ---- pool MFMA per rowgroup + relu + rowsum ----
    #pragma unroll
    for (int rg = 0; rg < 8; ++rg) {
        short8v a2[4];
        #pragma unroll
        for (int ks = 0; ks < 4; ++ks)
            a2[ks] = *reinterpret_cast<const short8v*>(
                &Asr[(rg * 16 + lr) * 136 + ks * 32 + kg * 8]);
        f32x4 pacc[4];
        #pragma unroll
        for (int ct = 0; ct < 4; ++ct) pacc[ct] = (f32x4)(0.f);
        #pragma unroll
        for (int ks = 0; ks < 4; ++ks)
            #pragma unroll
            for (int ct = 0; ct < 4; ++ct)
                pacc[ct] = __builtin_amdgcn_mfma_f32_16x16x32_bf16(
                    a2[ks], bfr[ct][ks], pacc[ct], 0, 0, 0);
        #pragma unroll
        for (int r = 0; r < 4; ++r) {
            float t = 0.f;
            #pragma unroll
            for (int ct = 0; ct < 4; ++ct) {
                const float v = pacc[ct][r] + bb1c[ct];
                t += v > 0.f ? v : 0.f;
            }
            t += __shfl_xor(t, 1); t += __shfl_xor(t, 2);
            t += __shfl_xor(t, 4); t += __shfl_xor(t, 8);
            if (lr == 0) redp[wid * 128 + rg * 16 + kg * 4 + r] = t;
        }
    }
    __syncthreads();

    if (tid < 128) {
        float p = redp[tid] + redp[128 + tid] + redp[256 + tid] + redp[384 + tid];
        const float mk = mask[row0 + tid];
        p = p * mk / mk;                  // reference NaN semantics
        alphap[tid] = 1.f / (1.f + expf(-p));
    }
    __syncthreads();

    // ---- gated = acc*q*alpha, single-rounded store ----
    #pragma unroll
    for (int m = 0; m < 4; ++m)
        #pragma unroll
        for (int r = 0; r < 4; ++r) {
            const int rowl = wr * 64 + m * 16 + kg * 4 + r;
            const float al = alphap[rowl];
            #pragma unroll
            for (int n = 0; n < 4; ++n) {
                outb[(row0 + rowl) * D_ + col0 + wc * 64 + n * 16 + lr] =
                    f2bf(acc[m][n][r] * qcol[n] * al);
            }
        }
}

// ---------------------------------------------------------------------------
// K4 (MFMA): logits[row] = relu(gated[row,:] @ Wa + ba) @ Wl + bl.
// 128 rows/block (256 blocks), 2 row-halves per wave.
// ---------------------------------------------------------------------------
__global__ __launch_bounds__(256)
void attn_logits_mfma(const unsigned short* __restrict__ gated,
                      const unsigned short* __restrict__ wat,
                      const float* __restrict__ ba, const float* __restrict__ Wl,
                      const float* __restrict__ bl, float* __restrict__ logits)
{
    __shared__ __align__(16) unsigned short Bs[64 * 256];   // 32 KB

    const int tid = threadIdx.x;
    const int l   = tid & 63;
    const int w   = tid >> 6;
    const int lr  = l & 15;
    const int kg  = l >> 4;
    const size_t arow0 = (size_t)blockIdx.x * 128 + w * 16 + lr;       // half 0
    const size_t arow1 = arow0 + 64;                                    // half 1

    const int sc  = tid >> 2;          // staging col 0..63
    const int sg0 = (tid & 3) * 8;     // staging granule base

    f32x4 acc[2][4];
    #pragma unroll
    for (int hh = 0; hh < 2; ++hh)
        #pragma unroll
        for (int ct = 0; ct < 4; ++ct) acc[hh][ct] = (f32x4)(0.f);

    for (int chunk = 0; chunk < 4; ++chunk) {
        const int k0 = chunk * 256;
        __syncthreads();
        #pragma unroll
        for (int i = 0; i < 8; ++i) {
            const int gr = sg0 + i;
            const ushort8v v = *reinterpret_cast<const ushort8v*>(
                &wat[(size_t)sc * 1024 + k0 + gr * 8]);
            *reinterpret_cast<ushort8v*>(&Bs[sc * 256 + ((gr ^ (sc & 7)) << 3)]) = v;
        }
        __syncthreads();
        #pragma unroll
        for (int ks = 0; ks < 8; ++ks) {
            const short8v a0 = *reinterpret_cast<const short8v*>(
                &gated[arow0 * D_ + k0 + ks * 32 + kg * 8]);
            const short8v a1 = *reinterpret_cast<const short8v*>(
                &gated[arow1 * D_ + k0 + ks * 32 + kg * 8]);
            #pragma unroll
            for (int ct = 0; ct < 4; ++ct) {
                const int c  = ct * 16 + lr;
                const int gr = ks * 4 + kg;
                const short8v b = *reinterpret_cast<const short8v*>(
                    &Bs[c * 256 + ((gr ^ (c & 7)) << 3)]);
                acc[0][ct] = __builtin_amdgcn_mfma_f32_16x16x32_bf16(a0, b, acc[0][ct], 0, 0, 0);
                acc[1][ct] = __builtin_amdgcn_mfma_f32_16x16x32_bf16(a1, b, acc[1][ct], 0, 0, 0);
            }
        }
    }

    float bac[4], wlc[4];
    #pragma unroll
    for (int ct = 0; ct < 4; ++ct) {
        const int c = ct * 16 + lr;
        bac[ct] = ba[c]; wlc[ct] = Wl[c];
    }
    const float bl0 = bl[0];
    #pragma unroll
    for (int hh = 0; hh < 2; ++hh)
        #pragma unroll
        for (int r = 0; r < 4; ++r) {
            float t = 0.f;
            #pragma unroll
            for (int ct = 0; ct < 4; ++ct) {
                float v = acc[hh][ct][r] + bac[ct];
                v = v > 0.f ? v : 0.f;
                t += v * wlc[ct];
            }
            t += __shfl_xor(t, 1); t += __shfl_xor(t, 2);
            t += __shfl_xor(t, 4); t += __shfl_xor(t, 8);
            if (lr == 0)
                logits[blockIdx.x * 128 + hh * 64 + w * 16 + kg * 4 + r] = t + bl0;
        }
}

// ---------------------------------------------------------------------------
// K5b: fused softmax-stats + partial weighted sums.
// ---------------------------------------------------------------------------
__global__ __launch_bounds__(256)
void weighted_partial(const unsigned short* __restrict__ gated,
                      const float* __restrict__ logits,
                      float* __restrict__ part)
{
    __shared__ float red[256];
    __shared__ float w[32];
    const int b  = blockIdx.x >> 5;
    const int ch = blockIdx.x & 31;
    const int tid = threadIdx.x;

    // block-wide max over this batch's 1024 logits
    const float4 lg = *reinterpret_cast<const float4*>(&logits[b * M_ + tid * 4]);
    float mx = fmaxf(fmaxf(lg.x, lg.y), fmaxf(lg.z, lg.w));
    red[tid] = mx; __syncthreads();
    for (int s = 128; s > 0; s >>= 1) {
        if (tid < s) red[tid] = fmaxf(red[tid], red[tid + s]);
        __syncthreads();
    }
    mx = red[0]; __syncthreads();
    // block-wide denom
    float sm = expf(lg.x - mx) + expf(lg.y - mx) + expf(lg.z - mx) + expf(lg.w - mx);
    red[tid] = sm; __syncthreads();
    for (int s = 128; s > 0; s >>= 1) {
        if (tid < s) red[tid] += red[tid + s];
        __syncthreads();
    }
    const float dn = red[0];
    __syncthreads();

    if (tid < 32) {
        const int m = ch * 32 + tid;
        w[tid] = expf(logits[b * M_ + m] - mx) / dn;
    }
    __syncthreads();

    float acc[4] = {0.f, 0.f, 0.f, 0.f};
    const int d0 = tid * 4;
    for (int m = 0; m < 32; ++m) {
        const float wm = w[m];
        const ushort4v g4 = *reinterpret_cast<const ushort4v*>(
            &gated[(size_t)(b * M_ + ch * 32 + m) * D_ + d0]);
        acc[0] += wm * bf2f(g4[0]); acc[1] += wm * bf2f(g4[1]);
        acc[2] += wm * bf2f(g4[2]); acc[3] += wm * bf2f(g4[3]);
    }
    #pragma unroll
    for (int dd = 0; dd < 4; ++dd)
        part[(size_t)blockIdx.x * D_ + d0 + dd] = acc[dd];
}

// ---------------------------------------------------------------------------
// K5c: final reduce (32 partials per batch)
// ---------------------------------------------------------------------------
__global__ __launch_bounds__(256)
void final_reduce(const float* __restrict__ part, float* __restrict__ out)
{
    const int i = blockIdx.x * 256 + threadIdx.x;
    const int b = i >> 10, d = i & 1023;
    float s = 0.f;
    #pragma unroll
    for (int c = 0; c < 32; ++c) s += part[(size_t)(b*32 + c) * D_ + d];
    out[i] = s;
}

// ---------------------------------------------------------------------------
extern "C" void kernel_launch(void* const* d_in, const int* in_sizes, int n_in,
                              void* d_out, int out_size, void* d_ws, size_t ws_size,
                              hipStream_t stream)
{
    const float* query = (const float*)d_in[0];
    const float* key   = (const float*)d_in[1];
    const float* mask  = (const float*)d_in[2];
    const float* Wq  = (const float*)d_in[5];
    const float* bq  = (const float*)d_in[6];
    const float* gqw = (const float*)d_in[7];
    const float* gqb = (const float*)d_in[8];
    const float* Wk  = (const float*)d_in[9];
    const float* bk  = (const float*)d_in[10];
    const float* gkw = (const float*)d_in[11];
    const float* gkb = (const float*)d_in[12];
    const float* Wb1 = (const float*)d_in[21];
    const float* bb1 = (const float*)d_in[22];
    const float* Wa  = (const float*)d_in[23];
    const float* ba  = (const float*)d_in[24];
    const float* Wl  = (const float*)d_in[25];
    const float* bl  = (const float*)d_in[26];

    float* ws = (float*)d_ws;
    float* qbuf   = ws;                        //  32768 f
    float* logits = ws + 32768;                //  32768 f
    unsigned short* keyb = (unsigned short*)(ws + 327744);   // 33554432 bf16
    unsigned short* wtb  = keyb + 33554432;                  //  1048576 bf16
    unsigned short* kbuf = wtb + 1048576;                    // 33554432 bf16 (gated)
    unsigned short* wb1t = kbuf + 33554432;                  //    32768 bf16
    unsigned short* wat  = wb1t + 32768;                     //    65536 bf16
    float* part = (float*)keyb;   // keyb dead after gemm_fused; 4MB << 67MB

    // key convert: zero-LDS, full occupancy (memory-bound)
    f32_to_bf16_vec<<<16384, 256, 0, stream>>>(key, keyb);
    // weight transposes + q path in one small launch
    prep_wq<<<288, 256, 0, stream>>>(Wk, wtb, Wb1, wb1t, Wa, wat,
                                     query, Wq, bq, gqw, gqb, qbuf);

    // fused: k-proj + GN + pool + gate -> gated (kbuf); same-XCD swizzled grid
    gemm_fused<<<2048, 256, 0, stream>>>(keyb, wtb, bk, gkw, gkb,
                                         qbuf, wb1t, bb1, mask, kbuf);

    // logits (MFMA, 128 rows/block)
    attn_logits_mfma<<<256, 256, 0, stream>>>(kbuf, wat, ba, Wl, bl, logits);

    // fused softmax + weighted sum, then reduce
    weighted_partial<<<1024, 256, 0, stream>>>(kbuf, logits, part);
    final_reduce<<<128, 256, 0, stream>>>(part, (float*)d_out);
}